// Round 1
// baseline (171.912 us; speedup 1.0000x reference)
//
#include <hip/hip_runtime.h>
#include <hip/hip_bf16.h>

#define BB    4
#define NN    16384
#define DD    128
#define HH    8
#define DHH   64
#define INNER 512
#define PC    64          // K^T V row-chunks per batch (K1 main grid = BB*PC = 256)

typedef __attribute__((ext_vector_type(8))) short bf16x8;
typedef __attribute__((ext_vector_type(4))) short short4_t;
typedef __attribute__((ext_vector_type(4))) float f32x4;
typedef unsigned short ushort_t;

#define MFMA(a, b, c) __builtin_amdgcn_mfma_f32_16x16x32_bf16((a), (b), (c), 0, 0, 0)

// fp32 -> bf16 round-to-nearest-even
__device__ __forceinline__ short f2bf(float x) {
    union { float f; unsigned u; } v; v.f = x;
    unsigned u = v.u;
    u += 0x7fffu + ((u >> 16) & 1u);
    return (short)(u >> 16);
}

__device__ __forceinline__ float bf2f(ushort_t us) {
    union { unsigned u; float f; } v;
    v.u = ((unsigned)us) << 16;
    return v.f;
}

// 8 consecutive floats at p -> bf16x8 (A-row / B-row fragment)
__device__ __forceinline__ bf16x8 load_row8(const float* __restrict__ p) {
    f32x4 a = *(const f32x4*)p;
    f32x4 b = *(const f32x4*)(p + 4);
    bf16x8 r;
    r[0] = f2bf(a[0]); r[1] = f2bf(a[1]); r[2] = f2bf(a[2]); r[3] = f2bf(a[3]);
    r[4] = f2bf(b[0]); r[5] = f2bf(b[1]); r[6] = f2bf(b[2]); r[7] = f2bf(b[3]);
    return r;
}

// 8 floats strided by `stride` elements -> bf16x8 (column fragment, global)
__device__ __forceinline__ bf16x8 load_col8(const float* __restrict__ p, int stride) {
    bf16x8 r;
#pragma unroll
    for (int j = 0; j < 8; ++j) r[j] = f2bf(p[(size_t)j * stride]);
    return r;
}

// ---------------------------------------------------------------------------
// K1: blocks [0,256): partial S[b] = keys[b]^T @ values[b] over a 256-row
// chunk, bf16 out.
//   R3 change: K/V tiles are now staged through LDS with coalesced
//   global_load_dwordx4 (16B/lane) + single bf16 conversion at staging,
//   replacing 48 strided scalar global loads per wave-iteration.
//   Double-buffered, T14 ordering (issue loads early, ds_write late).
// Blocks [256,272): head-factor producers (weights only), unchanged:
//   A_h  = Wq_h^T @ Wk_h            (128x128, K=64)   -> Abf  row-major [c'][c]
//   B'_h = Wk_h^T @ Wo_h^T, stored transposed: BT[cout][cin] (K=64)
// ---------------------------------------------------------------------------
__global__ __launch_bounds__(512) void k1_partialS_ab(
        const float* __restrict__ keys, const float* __restrict__ vals,
        const float* __restrict__ Wq, const float* __restrict__ Wk,
        const float* __restrict__ Wo,
        ushort_t* __restrict__ partial, ushort_t* __restrict__ Abf,
        ushort_t* __restrict__ BTbf) {
    const int lane = threadIdx.x & 63;
    const int w    = threadIdx.x >> 6;   // 0..7
    const int ml   = lane & 15;
    const int quad = lane >> 4;

    // pitch 132 bf16 (264 B): b64-write aligned; column reads <=4-way bank alias
    __shared__ short tK[2][32][132];
    __shared__ short tV[2][32][132];

    if (blockIdx.x < BB * PC) {
        // ---- partial S ----
        const int b     = blockIdx.x >> 6;
        const int chunk = blockIdx.x & (PC - 1);
        const int r0    = chunk * (NN / PC);      // 256 rows per block
        const int mw    = w & 3;
        const int nw    = w >> 2;

        const float* kbase = keys + (size_t)b * NN * DD;
        const float* vbase = vals + (size_t)b * NN * DD;

        const int lin0 = (int)threadIdx.x;        // covers 1024 float4 / tile with it=0,1
        const int ca0  = (2 * mw + 0) * 16 + ml;
        const int ca1  = (2 * mw + 1) * 16 + ml;

        f32x4 acc[2][4];
#pragma unroll
        for (int i = 0; i < 2; ++i)
#pragma unroll
            for (int t = 0; t < 4; ++t) acc[i][t] = (f32x4){0.f, 0.f, 0.f, 0.f};

        // ---- prologue: stage rows [r0, r0+32) into buffer 0 ----
        {
            const float* kp = kbase + (size_t)r0 * DD;
            const float* vp = vbase + (size_t)r0 * DD;
#pragma unroll
            for (int it = 0; it < 2; ++it) {
                const int lin = lin0 + it * 512;
                const int row = lin >> 5;
                const int c4  = (lin & 31) << 2;
                f32x4 kk = *(const f32x4*)(kp + (size_t)row * DD + c4);
                f32x4 vv = *(const f32x4*)(vp + (size_t)row * DD + c4);
                short4_t ks, vs;
#pragma unroll
                for (int j = 0; j < 4; ++j) { ks[j] = f2bf(kk[j]); vs[j] = f2bf(vv[j]); }
                *(short4_t*)&tK[0][row][c4] = ks;
                *(short4_t*)&tV[0][row][c4] = vs;
            }
        }
        __syncthreads();

        for (int s = 0; s < 8; ++s) {
            const int cur  = s & 1;
            const bool more = (s < 7);

            // T14 part A: issue next tile's global loads BEFORE compute
            f32x4 kreg[2], vreg[2];
            if (more) {
                const float* kp = kbase + (size_t)(r0 + (s + 1) * 32) * DD;
                const float* vp = vbase + (size_t)(r0 + (s + 1) * 32) * DD;
#pragma unroll
                for (int it = 0; it < 2; ++it) {
                    const int lin = lin0 + it * 512;
                    const int row = lin >> 5;
                    const int c4  = (lin & 31) << 2;
                    kreg[it] = *(const f32x4*)(kp + (size_t)row * DD + c4);
                    vreg[it] = *(const f32x4*)(vp + (size_t)row * DD + c4);
                }
            }

            // compute on current buffer (ds_read_u16 column fragments + MFMA)
            {
                bf16x8 a0, a1;
#pragma unroll
                for (int j = 0; j < 8; ++j) {
                    a0[j] = tK[cur][quad * 8 + j][ca0];
                    a1[j] = tK[cur][quad * 8 + j][ca1];
                }
#pragma unroll
                for (int t = 0; t < 4; ++t) {
                    const int cb = (nw * 4 + t) * 16 + ml;
                    bf16x8 bf;
#pragma unroll
                    for (int j = 0; j < 8; ++j) bf[j] = tV[cur][quad * 8 + j][cb];
                    acc[0][t] = MFMA(a0, bf, acc[0][t]);
                    acc[1][t] = MFMA(a1, bf, acc[1][t]);
                }
            }

            // T14 part B: convert + ds_write AFTER compute, behind a barrier
            if (more) {
                __syncthreads();   // everyone done reading buf cur^1 (last read: iter s-1)
                const int nb = cur ^ 1;
#pragma unroll
                for (int it = 0; it < 2; ++it) {
                    const int lin = lin0 + it * 512;
                    const int row = lin >> 5;
                    const int c4  = (lin & 31) << 2;
                    short4_t ks, vs;
#pragma unroll
                    for (int j = 0; j < 4; ++j) {
                        ks[j] = f2bf(kreg[it][j]);
                        vs[j] = f2bf(vreg[it][j]);
                    }
                    *(short4_t*)&tK[nb][row][c4] = ks;
                    *(short4_t*)&tV[nb][row][c4] = vs;
                }
                __syncthreads();   // writes visible before next compute
            }
        }

        ushort_t* outp = partial + (size_t)blockIdx.x * DD * DD;
#pragma unroll
        for (int i = 0; i < 2; ++i) {
            const int mrow = (2 * mw + i) * 16 + quad * 4;
#pragma unroll
            for (int t = 0; t < 4; ++t) {
                const int col = (nw * 4 + t) * 16 + ml;
#pragma unroll
                for (int r = 0; r < 4; ++r)
                    outp[(size_t)(mrow + r) * DD + col] = (ushort_t)f2bf(acc[i][t][r]);
            }
        }
    } else {
        // ---- head-factor producer (weights only, unchanged) ----
        const int ab    = blockIdx.x - BB * PC;   // 0..15
        const int h     = ab & 7;
        const int which = ab >> 3;                // 0 -> A_h, 1 -> BT_h
        const float* Wkh = Wk + (size_t)h * DHH * DD;

        f32x4 acc[8];
#pragma unroll
        for (int t = 0; t < 8; ++t) acc[t] = (f32x4){0.f, 0.f, 0.f, 0.f};

        if (which == 0) {
            // A_h[c'][c] = sum_d Wq[h64+d][c'] * Wk[h64+d][c]; m=c', n=c, k=d
            const float* Wqh = Wq + (size_t)h * DHH * DD;
#pragma unroll
            for (int kc = 0; kc < 2; ++kc) {
                const int d0 = kc * 32 + quad * 8;
                bf16x8 a = load_col8(Wqh + (size_t)d0 * DD + w * 16 + ml, DD);
#pragma unroll
                for (int t = 0; t < 8; ++t) {
                    bf16x8 bf = load_col8(Wkh + (size_t)d0 * DD + t * 16 + ml, DD);
                    acc[t] = MFMA(a, bf, acc[t]);
                }
            }
            ushort_t* dst = Abf + (size_t)h * DD * DD;
#pragma unroll
            for (int t = 0; t < 8; ++t)
#pragma unroll
                for (int r = 0; r < 4; ++r)
                    dst[(size_t)(w * 16 + quad * 4 + r) * DD + t * 16 + ml] =
                        (ushort_t)f2bf(acc[t][r]);
        } else {
            // B'_h[cin][cout] = sum_e Wk[h64+e][cin] * Wo[cout][h64+e]
            // computed with m=cout, n=cin -> stored BT[cout][cin]
#pragma unroll
            for (int kc = 0; kc < 2; ++kc) {
                const int e0 = kc * 32 + quad * 8;
                bf16x8 a = load_row8(Wo + (size_t)(w * 16 + ml) * INNER + h * DHH + e0);
#pragma unroll
                for (int t = 0; t < 8; ++t) {
                    bf16x8 bf = load_col8(Wkh + (size_t)e0 * DD + t * 16 + ml, DD);
                    acc[t] = MFMA(a, bf, acc[t]);
                }
            }
            ushort_t* dst = BTbf + (size_t)h * DD * DD;
#pragma unroll
            for (int t = 0; t < 8; ++t)
#pragma unroll
                for (int r = 0; r < 4; ++r)
                    dst[(size_t)(w * 16 + quad * 4 + r) * DD + t * 16 + ml] =
                        (ushort_t)f2bf(acc[t][r]);
        }
    }
}

// ---------------------------------------------------------------------------
// K2: S[b] = sum of PC bf16 partials (fp32 accum); also zero G.
// Grid: 256 blocks x 256 threads — one output element per thread.
// ---------------------------------------------------------------------------
__global__ __launch_bounds__(256) void k2_reduce(
        const ushort_t* __restrict__ partial, float* __restrict__ S,
        float* __restrict__ G) {
    const int t   = blockIdx.x * 256 + threadIdx.x;  // 0..65535
    const int b   = t >> 14;
    const int idx = t & 16383;
    const ushort_t* p = partial + ((size_t)b * PC) * DD * DD + idx;
    float s = 0.f;
#pragma unroll 16
    for (int c = 0; c < PC; ++c) s += bf2f(p[(size_t)c * DD * DD]);
    S[t] = s;
    G[t] = 0.f;
}

// ---------------------------------------------------------------------------
// K3: G[b] += A_h @ S[b] @ B'_h per (b,h) — two dependent stages only.
//   stage1: T = A_h @ S[b]      (128x128, K=128)  -> LDS bf16 A-layout
//   stage2: G += T @ B'_h       (128x128, K=128)  -> fp32 atomicAdd
// Grid: 32 blocks x 256 threads.
// ---------------------------------------------------------------------------
__global__ __launch_bounds__(256) void k3_middle(
        const float* __restrict__ S, const ushort_t* __restrict__ Abf,
        const ushort_t* __restrict__ BTbf, float* __restrict__ G) {
    const int b    = blockIdx.x >> 3;
    const int h    = blockIdx.x & 7;
    const int lane = threadIdx.x & 63;
    const int w    = threadIdx.x >> 6;   // 0..3
    const int ml   = lane & 15;
    const int quad = lane >> 4;

    __shared__ short T[128 * 136];       // T[c'][c''] A-layout, pitch 136

    const float*    Sb = S    + (size_t)b * DD * DD;
    const ushort_t* Ah = Abf  + (size_t)h * DD * DD;
    const ushort_t* Bh = BTbf + (size_t)h * DD * DD;

    // stage1: T = A_h @ S[b]. wave w -> m-tiles {2w,2w+1} x 8 n-tiles.
    {
        f32x4 acc[2][8];
#pragma unroll
        for (int i = 0; i < 2; ++i)
#pragma unroll
            for (int t = 0; t < 8; ++t) acc[i][t] = (f32x4){0.f, 0.f, 0.f, 0.f};
#pragma unroll
        for (int kc = 0; kc < 4; ++kc) {
            const int c0 = kc * 32 + quad * 8;
            bf16x8 a[2];
#pragma unroll
            for (int i = 0; i < 2; ++i)
                a[i] = *(const bf16x8*)&Ah[(size_t)((2 * w + i) * 16 + ml) * DD + c0];
#pragma unroll
            for (int t = 0; t < 8; ++t) {
                // B[k=c][n=c''] = S[c][c'']: column of S, stride 128
                bf16x8 bf = load_col8(Sb + (size_t)c0 * DD + t * 16 + ml, DD);
                acc[0][t] = MFMA(a[0], bf, acc[0][t]);
                acc[1][t] = MFMA(a[1], bf, acc[1][t]);
            }
        }
#pragma unroll
        for (int i = 0; i < 2; ++i)
#pragma unroll
            for (int t = 0; t < 8; ++t)
#pragma unroll
                for (int r = 0; r < 4; ++r)
                    T[((2 * w + i) * 16 + quad * 4 + r) * 136 + t * 16 + ml] =
                        f2bf(acc[i][t][r]);
    }
    __syncthreads();

    // stage2: G += T @ B'_h.  B[k=cin][n=cout] = BT[cout][cin] rows.
    {
        f32x4 acc[2][8];
#pragma unroll
        for (int i = 0; i < 2; ++i)
#pragma unroll
            for (int t = 0; t < 8; ++t) acc[i][t] = (f32x4){0.f, 0.f, 0.f, 0.f};
#pragma unroll
        for (int kc = 0; kc < 4; ++kc) {
            const int k0 = kc * 32 + quad * 8;
            bf16x8 a[2];
#pragma unroll
            for (int i = 0; i < 2; ++i)
                a[i] = *(const bf16x8*)&T[((2 * w + i) * 16 + ml) * 136 + k0];
#pragma unroll
            for (int t = 0; t < 8; ++t) {
                bf16x8 bf = *(const bf16x8*)&Bh[(size_t)(t * 16 + ml) * DD + k0];
                acc[0][t] = MFMA(a[0], bf, acc[0][t]);
                acc[1][t] = MFMA(a[1], bf, acc[1][t]);
            }
        }
        float* Gb = G + (size_t)b * DD * DD;
#pragma unroll
        for (int i = 0; i < 2; ++i)
#pragma unroll
            for (int t = 0; t < 8; ++t)
#pragma unroll
                for (int r = 0; r < 4; ++r)
                    atomicAdd(&Gb[((2 * w + i) * 16 + quad * 4 + r) * DD + t * 16 + ml],
                              acc[i][t][r]);
    }
}

// ---------------------------------------------------------------------------
// K4: out[b] = queries[b] @ (G[b]/N) + bo.
// Grid: 256 blocks x 512 threads; block covers 256 rows (one Gt staging per
// 256 rows). G staged to LDS transposed+scaled (1/N = 2^-14 exact).
// ---------------------------------------------------------------------------
__global__ __launch_bounds__(512) void k4_final(
        const float* __restrict__ queries, const float* __restrict__ G,
        const float* __restrict__ bo, float* __restrict__ outp) {
    const int b  = blockIdx.x >> 6;
    const int r0 = (blockIdx.x & 63) * 256;

    __shared__ short Gt[128 * 136];   // Gt[c][c'] = G[c'][c] * invN  (B-layout)
    {
        const float* Gb = G + (size_t)b * DD * DD;
        const float invN = 6.103515625e-05f;  // 1/16384
#pragma unroll 4
        for (int it = 0; it < 32; ++it) {
            const int idx = threadIdx.x + it * 512;
            const int cp = idx >> 7, c = idx & 127;
            Gt[c * 136 + cp] = f2bf(Gb[idx] * invN);
        }
    }
    __syncthreads();

    const int lane = threadIdx.x & 63;
    const int w    = threadIdx.x >> 6;   // 0..7 -> row tiles {2w, 2w+1}
    const int ml   = lane & 15;
    const int quad = lane >> 4;
    const float* qbase = queries + ((size_t)b * NN + r0) * DD;

    f32x4 acc[2][8];
#pragma unroll
    for (int i = 0; i < 2; ++i)
#pragma unroll
        for (int t = 0; t < 8; ++t) acc[i][t] = (f32x4){0.f, 0.f, 0.f, 0.f};

#pragma unroll
    for (int kc = 0; kc < 4; ++kc) {
        const int k0 = kc * 32 + quad * 8;
        bf16x8 a[2];
#pragma unroll
        for (int i = 0; i < 2; ++i)
            a[i] = load_row8(qbase + (size_t)((2 * w + i) * 16 + ml) * DD + k0);
#pragma unroll
        for (int t = 0; t < 8; ++t) {
            bf16x8 bf = *(const bf16x8*)&Gt[(t * 16 + ml) * 136 + k0];
            acc[0][t] = MFMA(a[0], bf, acc[0][t]);
            acc[1][t] = MFMA(a[1], bf, acc[1][t]);
        }
    }

    float* ob = outp + ((size_t)b * NN + r0) * DD;
#pragma unroll
    for (int t = 0; t < 8; ++t) {
        const int c = t * 16 + ml;
        const float boc = bo[c];
#pragma unroll
        for (int i = 0; i < 2; ++i)
#pragma unroll
            for (int r = 0; r < 4; ++r)
                ob[(size_t)((2 * w + i) * 16 + quad * 4 + r) * DD + c] =
                    acc[i][t][r] + boc;
    }
}

extern "C" void kernel_launch(void* const* d_in, const int* in_sizes, int n_in,
                              void* d_out, int out_size, void* d_ws, size_t ws_size,
                              hipStream_t stream) {
    const float* queries = (const float*)d_in[0];
    const float* keys    = (const float*)d_in[1];
    const float* values  = (const float*)d_in[2];
    const float* Wq      = (const float*)d_in[3];
    const float* Wk      = (const float*)d_in[4];
    const float* Wo      = (const float*)d_in[5];
    const float* bo      = (const float*)d_in[6];
    float* out = (float*)d_out;

    // ws: [S f32][G f32][Abf bf16 x8][BTbf bf16 x8][partial bf16]
    float* S = (float*)d_ws;
    float* G = S + (size_t)BB * DD * DD;
    ushort_t* Abf     = (ushort_t*)(G + (size_t)BB * DD * DD);
    ushort_t* BTbf    = Abf  + (size_t)HH * DD * DD;
    ushort_t* partial = BTbf + (size_t)HH * DD * DD;

    hipLaunchKernelGGL(k1_partialS_ab, dim3(BB * PC + 16), dim3(512), 0, stream,
                       keys, values, Wq, Wk, Wo, partial, Abf, BTbf);
    hipLaunchKernelGGL(k2_reduce, dim3(256), dim3(256), 0, stream,
                       partial, S, G);
    hipLaunchKernelGGL(k3_middle, dim3(BB * HH), dim3(256), 0, stream,
                       S, Abf, BTbf, G);
    hipLaunchKernelGGL(k4_final, dim3(256), dim3(512), 0, stream,
                       queries, G, bo, out);
}